// Round 5
// baseline (567.995 us; speedup 1.0000x reference)
//
#include <hip/hip_runtime.h>

#define T_STEPS 1024
#define BATCH   1024
#define NS      64
#define CPB     16                      // chains per block
#define NBLK    (BATCH / CPB)           // 64 blocks
#define TS      ((size_t)BATCH * NS)    // floats per timestep plane

typedef __attribute__((ext_vector_type(8))) __bf16 bf16x8;
typedef __attribute__((ext_vector_type(4))) __bf16 bf16x4;
typedef __attribute__((ext_vector_type(4))) float  f32x4;

// ds_swizzle BitMode xor-16 within each 32-lane group
#define SWZ_XOR16 0x401F
__device__ __forceinline__ float swz16f(float x) {
    return __uint_as_float((unsigned)__builtin_amdgcn_ds_swizzle(
        (int)__float_as_uint(x), SWZ_XOR16));
}

// v9: MFMA reformulation. 16 chains per wave, lane l: c = l&15 (chain),
// g = l>>4. Exp-domain recurrence U' = (E.U) o exp(em_t), E = exp(trans)
// held as 8 bf16 A-fragments (4 row-tiles x 2 K-slices). U round-trips
// through a 2KB LDS buffer per step:
//   write: D-layout (state 16*mt+4*g+i, chain c) as bf16x4 @ swizzled chunk
//   read : B-fragments (8 contiguous states, chain c)   @ swizzled chunk
// Swizzle: XOR the state-chunk index (s>>3) with (c&7) -> bank-optimal for
// both the b64 writes and b128 reads (without it: 16-way conflicts).
// Fragment maps (gfx950 16x16x32, per AMD matrix calculator + m89-verified D):
//   A: row = l&15,          k = 8*(l>>4)+e
//   B: col = l&15,          k = 8*(l>>4)+e
//   D: col = l&15,          row = 4*(l>>4)+reg
// em is f32 throughout (exp'd on VALU), prefetched 4 steps deep in registers
// (static ring indices via unroll-4 groups). Per-chain renorm every 4 steps
// (cross-lane max over the 4 lanes of a chain); per-chain logZ captured at
// t == Lc-1 (columns of finished chains keep evolving harmlessly; NaN/Inf in
// a dead column cannot cross columns in E.U).
__global__ __launch_bounds__(64)
void crf_fwd_v9(const float* __restrict__ em,     // [T, B, S]
                const int*   __restrict__ seqlen, // [B]
                const float* __restrict__ start,  // [S]
                const float* __restrict__ stop,   // [S]
                const float* __restrict__ trans,  // [S, S]
                float*       __restrict__ out) {  // [B]
    __shared__ __align__(16) char Ulds[CPB * 128];   // 16 rows x 64 bf16

    const int l  = threadIdx.x;
    const int c  = l & 15;
    const int g  = l >> 4;
    const int b0 = blockIdx.x * CPB;
    const int Lc = seqlen[b0 + c];
    const int c7 = c & 7;

    // ---- E as bf16 A-fragments ----
    bf16x8 ae[4][2];
#pragma unroll
    for (int mt = 0; mt < 4; ++mt)
#pragma unroll
        for (int ks = 0; ks < 2; ++ks) {
            const float* tp = trans + (size_t)(16 * mt + c) * NS + 32 * ks + 8 * g;
            f32x4 t0 = *(const f32x4*)tp;
            f32x4 t1 = *(const f32x4*)(tp + 4);
            bf16x8 a;
            a[0] = (__bf16)__expf(t0[0]); a[1] = (__bf16)__expf(t0[1]);
            a[2] = (__bf16)__expf(t0[2]); a[3] = (__bf16)__expf(t0[3]);
            a[4] = (__bf16)__expf(t1[0]); a[5] = (__bf16)__expf(t1[1]);
            a[6] = (__bf16)__expf(t1[2]); a[7] = (__bf16)__expf(t1[3]);
            ae[mt][ks] = a;
        }

    // ---- exp(stop), start per lane ----
    float es[4][4], st0[4][4];
#pragma unroll
    for (int mt = 0; mt < 4; ++mt) {
        f32x4 sv = *(const f32x4*)(stop  + 16 * mt + 4 * g);
        f32x4 tv = *(const f32x4*)(start + 16 * mt + 4 * g);
#pragma unroll
        for (int i = 0; i < 4; ++i) { es[mt][i] = __expf(sv[i]); st0[mt][i] = tv[i]; }
    }

    // ---- LDS byte offsets (state-chunk XOR c&7 swizzle) ----
    char* ub = (char*)Ulds;
    int woff[4], boff[2];
#pragma unroll
    for (int mt = 0; mt < 4; ++mt)
        woff[mt] = c * 128 + ((((2 * mt + (g >> 1)) ^ c7) << 4) | ((g & 1) << 3));
#pragma unroll
    for (int ks = 0; ks < 2; ++ks)
        boff[ks] = c * 128 + (((4 * ks + g) ^ c7) << 4);

    // ---- em pointers + 4-deep register ring ----
    const float* emp[4];
#pragma unroll
    for (int mt = 0; mt < 4; ++mt)
        emp[mt] = em + (size_t)(b0 + c) * NS + 16 * mt + 4 * g;

    f32x4 emb[4][4];
#pragma unroll
    for (int S = 0; S < 4; ++S)
#pragma unroll
        for (int mt = 0; mt < 4; ++mt)
            emb[S][mt] = *(const f32x4*)(emp[mt] + (size_t)S * TS);

#define CAPTURE_BODY(T_)                                                      \
    do {                                                                      \
        float dv = 0.f;                                                       \
        _Pragma("unroll") for (int m_ = 0; m_ < 4; ++m_)                      \
            _Pragma("unroll") for (int i_ = 0; i_ < 4; ++i_)                  \
                dv = fmaf(u[m_][i_], es[m_][i_], dv);                         \
        dv += swz16f(dv);                                                     \
        dv += __shfl_xor(dv, 32, 64);                                         \
        if ((T_) == Lc - 1 && g == 0) out[b0 + c] = __logf(dv) + c_acc;       \
    } while (0)

#define WRITE_READ()                                                          \
    do {                                                                      \
        bf16x4 p0, p1;                                                        \
        p0[0] = (__bf16)u[0][0]; p0[1] = (__bf16)u[0][1];                     \
        p0[2] = (__bf16)u[0][2]; p0[3] = (__bf16)u[0][3];                     \
        p1[0] = (__bf16)u[1][0]; p1[1] = (__bf16)u[1][1];                     \
        p1[2] = (__bf16)u[1][2]; p1[3] = (__bf16)u[1][3];                     \
        *(bf16x4*)(ub + woff[0]) = p0;                                        \
        *(bf16x4*)(ub + woff[1]) = p1;                                        \
        bfA = *(bf16x8*)(ub + boff[0]);                                       \
        p0[0] = (__bf16)u[2][0]; p0[1] = (__bf16)u[2][1];                     \
        p0[2] = (__bf16)u[2][2]; p0[3] = (__bf16)u[2][3];                     \
        p1[0] = (__bf16)u[3][0]; p1[1] = (__bf16)u[3][1];                     \
        p1[2] = (__bf16)u[3][2]; p1[3] = (__bf16)u[3][3];                     \
        *(bf16x4*)(ub + woff[2]) = p0;                                        \
        *(bf16x4*)(ub + woff[3]) = p1;                                        \
        bfB = *(bf16x8*)(ub + boff[1]);                                       \
    } while (0)

#define STEP(T_, SLOT_, RN_, LAST_)                                           \
    do {                                                                      \
        f32x4 zz = {0.f, 0.f, 0.f, 0.f};                                      \
        f32x4 acc[4];                                                         \
        _Pragma("unroll") for (int m_ = 0; m_ < 4; ++m_)                      \
            acc[m_] = __builtin_amdgcn_mfma_f32_16x16x32_bf16(                \
                ae[m_][0], bfA, zz, 0, 0, 0);                                 \
        _Pragma("unroll") for (int m_ = 0; m_ < 4; ++m_)                      \
            acc[m_] = __builtin_amdgcn_mfma_f32_16x16x32_bf16(                \
                ae[m_][1], bfB, acc[m_], 0, 0, 0);                            \
        if (RN_) {                                                            \
            float v1 = fmaxf(mloc, swz16f(mloc));                             \
            float mm = fmaxf(v1, __shfl_xor(v1, 32, 64));                     \
            mm  = fmaxf(mm, 1e-30f);                                          \
            inv = __builtin_amdgcn_rcpf(mm);                                  \
            c_acc += __logf(mm);                                              \
        }                                                                     \
        _Pragma("unroll") for (int m_ = 0; m_ < 4; ++m_)                      \
            _Pragma("unroll") for (int i_ = 0; i_ < 4; ++i_) {                \
                float exv = __expf(emb[SLOT_][m_][i_]);                       \
                if (RN_) exv *= inv;                                          \
                u[m_][i_] = acc[m_][i_] * exv;                                \
            }                                                                 \
        {   /* prefetch em for T_+4 (clamped; dead reads are harmless) */     \
            size_t tn = (size_t)(((T_) + 4 <= T_STEPS - 1) ? (T_) + 4         \
                                                           : T_STEPS - 1);    \
            _Pragma("unroll") for (int m_ = 0; m_ < 4; ++m_)                  \
                emb[SLOT_][m_] = *(const f32x4*)(emp[m_] + tn * TS);          \
        }                                                                     \
        if (__any((T_) == Lc - 1)) CAPTURE_BODY(T_);                          \
        if (LAST_) {                                                          \
            mloc = u[0][0];                                                   \
            _Pragma("unroll") for (int m_ = 0; m_ < 4; ++m_)                  \
                _Pragma("unroll") for (int i_ = 0; i_ < 4; ++i_)              \
                    mloc = fmaxf(mloc, u[m_][i_]);                            \
        }                                                                     \
        WRITE_READ();                                                         \
    } while (0)

    // ---- init (t = 0) ----
    float u[4][4];
#pragma unroll
    for (int mt = 0; mt < 4; ++mt)
#pragma unroll
        for (int i = 0; i < 4; ++i)
            u[mt][i] = __expf(st0[mt][i] + emb[0][mt][i]);
#pragma unroll
    for (int mt = 0; mt < 4; ++mt)       // slot 0 -> em[4]
        emb[0][mt] = *(const f32x4*)(emp[mt] + 4 * TS);

    float c_acc = 0.f, inv = 1.f;
    (void)inv;
    if (__any(0 == Lc - 1)) CAPTURE_BODY(0);

    float mloc = u[0][0];
#pragma unroll
    for (int mt = 0; mt < 4; ++mt)
#pragma unroll
        for (int i = 0; i < 4; ++i) mloc = fmaxf(mloc, u[mt][i]);

    bf16x8 bfA, bfB;
    WRITE_READ();

    // ---- main loop: t = 1..1024 (256 groups of 4; step 1024 is inert:
    // captures need t <= 1023, dead columns evolve harmlessly) ----
    for (int grp = 0; grp < 256; ++grp) {
        const int t0_ = 1 + 4 * grp;
        STEP(t0_ + 0, 1, 1, 0);
        STEP(t0_ + 1, 2, 0, 0);
        STEP(t0_ + 2, 3, 0, 0);
        STEP(t0_ + 3, 0, 0, 1);
    }
}

extern "C" void kernel_launch(void* const* d_in, const int* in_sizes, int n_in,
                              void* d_out, int out_size, void* d_ws, size_t ws_size,
                              hipStream_t stream) {
    const float* em     = (const float*)d_in[0]; // [T, B, S]
    const int*   seqlen = (const int*)  d_in[1]; // [B]
    const float* start  = (const float*)d_in[2]; // [S]
    const float* stop   = (const float*)d_in[3]; // [S]
    const float* trans  = (const float*)d_in[4]; // [S, S]
    float*       out    = (float*)d_out;         // [B]

    crf_fwd_v9<<<NBLK, 64, 0, stream>>>(em, seqlen, start, stop, trans, out);
}